// Round 9
// baseline (127.450 us; speedup 1.0000x reference)
//
#include <hip/hip_runtime.h>

#define IMH 512
#define IMW 512
#define PW 514                 // padded plane width/height
#define PS (PW * PW)           // 264,196 cells per plane
#define NCH 30                 // 3 (Z) + 27 (w_pre) channels
#define UOFF (IMH * IMW * 3)   // w-output offset in out

typedef float f4a __attribute__((ext_vector_type(4), aligned(4)));
typedef float f2a __attribute__((ext_vector_type(2), aligned(4)));

// R9: two-pass split through d_ws (ws >= 268MB per the harness poison fills;
// we use 31.7MB). The fused kernel's residual cost was structural: per-block
// phase serialization + 41% halo recompute. Pass A is a pure elementwise
// stream into a 514x514 ZERO-PADDED, CHANNEL-PLANAR intermediate (coalesced
// everything, no LDS, no barriers, no halo redundancy). Pass B convolves
// straight from the planes: all loads coalesced across lanes, padding kills
// all bounds logic, and each JVP group lives in only 3 accumulators at a time
// (compute -> JVP -> store -> reuse; anti-spill lesson from R2/R5/R7).

// ---------- Pass A: Bayes update + sensitivity quotient rule -> planar ws
__global__ __launch_bounds__(256, 4)
void hmm_stage_a(const float* __restrict__ obs,
                 const float* __restrict__ P,      // (S,O): P[o*3+s]
                 const float* __restrict__ u_k,
                 const float* __restrict__ w_k,    // pix*27 + s*9 + i*3 + j
                 float* __restrict__ ws) {
    const int cell = blockIdx.x * 256 + threadIdx.x;
    if (cell >= PS) return;
    const int y = cell / PW;
    const int x = cell - y * PW;

    if (y == 0 || y == PW - 1 || x == 0 || x == PW - 1) {
#pragma unroll
        for (int c = 0; c < NCH; ++c) ws[c * PS + cell] = 0.0f;  // SAME zero pad
        return;
    }

    float Pm[9];
#pragma unroll
    for (int i = 0; i < 9; ++i) Pm[i] = P[i];

    const int pix = (y - 1) * IMW + (x - 1);

    const f2a o01 = *(const f2a*)(obs + pix * 3);
    const float o2 = obs[pix * 3 + 2];
    const f2a u01 = *(const f2a*)(u_k + pix * 3);
    const float u2 = u_k[pix * 3 + 2];
    const float ov[3] = {o01.x, o01.y, o2};
    const float us[3] = {u01.x, u01.y, u2};

    // w_k slice: 27 floats as 6x float4 + float2 + float
    const float* wkp = &w_k[(size_t)pix * 27];
    float wreg[27];
    {
        const f4a* v4 = (const f4a*)wkp;
        const f4a a0 = v4[0], a1 = v4[1], a2 = v4[2], a3 = v4[3], a4 = v4[4], a5 = v4[5];
        const f2a a6 = *(const f2a*)(wkp + 24);
        const float a7 = wkp[26];
        wreg[0] = a0.x;  wreg[1] = a0.y;  wreg[2] = a0.z;  wreg[3] = a0.w;
        wreg[4] = a1.x;  wreg[5] = a1.y;  wreg[6] = a1.z;  wreg[7] = a1.w;
        wreg[8] = a2.x;  wreg[9] = a2.y;  wreg[10] = a2.z; wreg[11] = a2.w;
        wreg[12] = a3.x; wreg[13] = a3.y; wreg[14] = a3.z; wreg[15] = a3.w;
        wreg[16] = a4.x; wreg[17] = a4.y; wreg[18] = a4.z; wreg[19] = a4.w;
        wreg[20] = a5.x; wreg[21] = a5.y; wreg[22] = a5.z; wreg[23] = a5.w;
        wreg[24] = a6.x; wreg[25] = a6.y; wreg[26] = a7;
    }

    float b[3], Bu[3], bu = 0.0f;
#pragma unroll
    for (int s = 0; s < 3; ++s) {
        b[s] = Pm[0 * 3 + s] * ov[0] + Pm[1 * 3 + s] * ov[1] + Pm[2 * 3 + s] * ov[2];
        Bu[s] = b[s] * us[s];
        bu += Bu[s];
    }
    const float inv_bu = 1.0f / bu;
    float Z[3];
#pragma unroll
    for (int s = 0; s < 3; ++s) { Z[s] = Bu[s] * inv_bu; ws[s * PS + cell] = Z[s]; }

#pragma unroll
    for (int i = 0; i < 3; ++i) {
#pragma unroll
        for (int j = 0; j < 3; ++j) {
            const int ij = i * 3 + j;
            float du[3], sdu = 0.0f;
#pragma unroll
            for (int s = 0; s < 3; ++s) {
                float d = b[s] * wreg[s * 9 + ij];
                if (s == j) d += ov[i] * us[s];
                du[s] = d;
                sdu += d;
            }
#pragma unroll
            for (int s = 0; s < 3; ++s)
                ws[((1 + ij) * 3 + s) * PS + cell] = (du[s] - sdu * Z[s]) * inv_bu;
        }
    }
}

// ---------- Pass B: 3x3 conv per group + softmax + softmax-JVP, from planes
__global__ __launch_bounds__(256, 4)
void hmm_stage_b(const float* __restrict__ ws,
                 const float* __restrict__ conv_w, // (S_out,S_in,3,3)
                 const float* __restrict__ conv_b, // (S,)
                 float* __restrict__ out) {
    const int tid = threadIdx.x;
    const int half = tid >> 7;                 // waves 0,1 / waves 2,3
    const int pix = blockIdx.x * 128 + (tid & 127);
    const int h = pix >> 9, w = pix & 511;
    const int base = (h + 1) * PW + (w + 1);   // interior cell of this pixel

    float cw[81];                              // cw[s*27 + ci*9 + ky*3 + kx]
#pragma unroll
    for (int i = 0; i < 81; ++i) cw[i] = conv_w[i];
    const float cb0 = conv_b[0], cb1 = conv_b[1], cb2 = conv_b[2];

    // 27 FMAs of one 3-channel group; taps unrolled, offsets compile-time.
#define GCONV(G, A0, A1, A2)                                                      \
    {                                                                             \
        const float* q0 = ws + (3 * (G) + 0) * PS + base;                         \
        const float* q1 = ws + (3 * (G) + 1) * PS + base;                         \
        const float* q2 = ws + (3 * (G) + 2) * PS + base;                         \
        _Pragma("unroll")                                                         \
        for (int dy = -1; dy <= 1; ++dy) {                                        \
            _Pragma("unroll")                                                     \
            for (int dx = -1; dx <= 1; ++dx) {                                    \
                const int off = dy * PW + dx;                                     \
                const int T = (dy + 1) * 3 + (dx + 1);                            \
                const float v0 = q0[off], v1 = q1[off], v2 = q2[off];             \
                A0 += cw[0 + T] * v0 + cw[9 + T] * v1 + cw[18 + T] * v2;          \
                A1 += cw[27 + T] * v0 + cw[36 + T] * v1 + cw[45 + T] * v2;        \
                A2 += cw[54 + T] * v0 + cw[63 + T] * v1 + cw[72 + T] * v2;        \
            }                                                                     \
        }                                                                         \
    }

    // group 0 -> softmax (both halves; avoids a cross-wave p handoff)
    float y0 = cb0, y1 = cb1, y2 = cb2;
    GCONV(0, y0, y1, y2)
    const float m = fmaxf(y0, fmaxf(y1, y2));
    const float e0 = __expf(y0 - m), e1 = __expf(y1 - m), e2 = __expf(y2 - m);
    const float inv = 1.0f / (e0 + e1 + e2);
    const float p0 = e0 * inv, p1 = e1 * inv, p2 = e2 * inv;

    float* wp = out + UOFF + (size_t)pix * 27;

    // per group: conv -> JVP -> store, only 3 accumulators live at a time
#define GROUP_JVP(G, IJ)                                                          \
    {                                                                             \
        float a0 = 0.0f, a1 = 0.0f, a2 = 0.0f;                                    \
        GCONV(G, a0, a1, a2)                                                      \
        const float dot_ = p0 * a0 + p1 * a1 + p2 * a2;                           \
        wp[(IJ) + 0]  = p0 * (a0 - dot_);                                         \
        wp[(IJ) + 9]  = p1 * (a1 - dot_);                                         \
        wp[(IJ) + 18] = p2 * (a2 - dot_);                                         \
    }

    if (half == 0) {
        out[pix * 3 + 0] = p0; out[pix * 3 + 1] = p1; out[pix * 3 + 2] = p2;
        GROUP_JVP(1, 0) GROUP_JVP(2, 1) GROUP_JVP(3, 2) GROUP_JVP(4, 3)
    } else {
        GROUP_JVP(5, 4) GROUP_JVP(6, 5) GROUP_JVP(7, 6) GROUP_JVP(8, 7) GROUP_JVP(9, 8)
    }
#undef GROUP_JVP
#undef GCONV
}

extern "C" void kernel_launch(void* const* d_in, const int* in_sizes, int n_in,
                              void* d_out, int out_size, void* d_ws, size_t ws_size,
                              hipStream_t stream) {
    const float* obs    = (const float*)d_in[0];
    const float* P      = (const float*)d_in[1];
    const float* u_k    = (const float*)d_in[2];
    const float* w_k    = (const float*)d_in[3];
    const float* conv_w = (const float*)d_in[4];
    const float* conv_b = (const float*)d_in[5];
    float* out = (float*)d_out;
    float* ws  = (float*)d_ws;    // needs 30*PS*4 = 31.7 MB; harness provides ~268 MB

    const int blocksA = (PS + 255) / 256;          // 1033
    hmm_stage_a<<<blocksA, 256, 0, stream>>>(obs, P, u_k, w_k, ws);

    const int blocksB = (IMH * IMW) / 128;         // 2048
    hmm_stage_b<<<blocksB, 256, 0, stream>>>(ws, conv_w, conv_b, out);
}

// Round 10
// 105.093 us; speedup vs baseline: 1.2127x; 1.2127x over previous
//
#include <hip/hip_runtime.h>

#define IMH 512
#define IMW 512
#define TW 16
#define TH 8
#define HW_ (TW + 2)          // 18
#define HH_ (TH + 2)          // 10
#define NHALO (HW_ * HH_)     // 180
#define NPIX (TW * TH)        // 128 interior pixels per block
#define ROW 31                // padded floats per halo pixel (30 ch + 1 pad; gcd(31,32)=1)

typedef float f4 __attribute__((ext_vector_type(4)));
typedef float f4a __attribute__((ext_vector_type(4), aligned(4)));
typedef float f2a __attribute__((ext_vector_type(2), aligned(4)));

// R10 = R8 (best, 105.58us: fused, row-walk partial-sum conv) with phase B
// rebalanced to 100% lane utilization. R9's two-pass split regressed (+22us):
// inter-block overlap already hides phase serialization, so fused is right.
//   B0 (128 thr, 1/px): g0 conv + softmax -> u, p_aux; THEN group 9 conv+JVP
//       (fills B0's idle tail; B0 was the short phase).
//   B1 (256 thr = 16 cols x 8 groups x 2 row-halves): half L walks rows 0-5
//       -> outputs 0-3, half U walks rows 4-9 -> outputs 4-7. Longest phase's
//       serial depth ~halves (54 reads/thread vs 90). Same 3 rotating static
//       accumulator triplets (~40 live VGPR; anti-spill lesson R2/R5/R7).
// FMA order per output unchanged (ky chronological, kx-inner, ch-inner).
__global__ __launch_bounds__(256, 4)
void hmm_fused(const float* __restrict__ obs,
               const float* __restrict__ P,      // (S,O) indexed P[o*3+s] per einsum 'os,hwo->hws'
               const float* __restrict__ u_k,
               const float* __restrict__ w_k,    // (H,W,S,1,S,O) -> pix*27 + s*9 + i*3 + j
               const float* __restrict__ conv_w, // (S_out,S_in,3,3)
               const float* __restrict__ conv_b, // (S,)
               float* __restrict__ out) {        // [0, 512*512*3): u_kp1 ; rest: w_kp1_O
    __shared__ __align__(16) float lds[NHALO * ROW];   // 22,320 B
    __shared__ f4 p_aux4[NPIX];                        // 2,048 B (p0,p1,p2,pad)

    const int tid = threadIdx.x;
    const int w0 = blockIdx.x * TW;
    const int h0 = blockIdx.y * TH;

    // P into registers (wave-uniform -> SGPRs)
    float Pm[9];
#pragma unroll
    for (int i = 0; i < 9; ++i) Pm[i] = P[i];

    // ---------- Stage A: halo pixels -> Z (ch 0..2) and w_pre (ch 3..29) in LDS
    if (tid < NHALO) {
        const int p = tid;
        const int hh = h0 + p / HW_ - 1;
        const int ww = w0 + p % HW_ - 1;
        float* row = &lds[p * ROW];
        if (hh < 0 || hh >= IMH || ww < 0 || ww >= IMW) {
#pragma unroll
            for (int c = 0; c < 30; ++c) row[c] = 0.0f;   // SAME zero padding
        } else {
            const int pix = hh * IMW + ww;

            const f2a o01 = *(const f2a*)(obs + pix * 3);
            const float o2 = obs[pix * 3 + 2];
            const f2a u01 = *(const f2a*)(u_k + pix * 3);
            const float u2 = u_k[pix * 3 + 2];
            const float ov[3] = {o01.x, o01.y, o2};
            const float us[3] = {u01.x, u01.y, u2};

            // w_k slice: 27 floats as 6x float4 + float2 + float
            const float* wkp = &w_k[(size_t)pix * 27];
            float wreg[27];
            {
                const f4a* v4 = (const f4a*)wkp;
                const f4a a0 = v4[0], a1 = v4[1], a2 = v4[2], a3 = v4[3], a4 = v4[4], a5 = v4[5];
                const f2a a6 = *(const f2a*)(wkp + 24);
                const float a7 = wkp[26];
                wreg[0] = a0.x;  wreg[1] = a0.y;  wreg[2] = a0.z;  wreg[3] = a0.w;
                wreg[4] = a1.x;  wreg[5] = a1.y;  wreg[6] = a1.z;  wreg[7] = a1.w;
                wreg[8] = a2.x;  wreg[9] = a2.y;  wreg[10] = a2.z; wreg[11] = a2.w;
                wreg[12] = a3.x; wreg[13] = a3.y; wreg[14] = a3.z; wreg[15] = a3.w;
                wreg[16] = a4.x; wreg[17] = a4.y; wreg[18] = a4.z; wreg[19] = a4.w;
                wreg[20] = a5.x; wreg[21] = a5.y; wreg[22] = a5.z; wreg[23] = a5.w;
                wreg[24] = a6.x; wreg[25] = a6.y; wreg[26] = a7;
            }

            float b[3], Bu[3], bu = 0.0f;
#pragma unroll
            for (int s = 0; s < 3; ++s) {
                b[s] = Pm[0 * 3 + s] * ov[0] + Pm[1 * 3 + s] * ov[1] + Pm[2 * 3 + s] * ov[2];
                Bu[s] = b[s] * us[s];
                bu += Bu[s];
            }
            const float inv_bu = 1.0f / bu;
            float Z[3];
#pragma unroll
            for (int s = 0; s < 3; ++s) { Z[s] = Bu[s] * inv_bu; row[s] = Z[s]; }

#pragma unroll
            for (int i = 0; i < 3; ++i) {
#pragma unroll
                for (int j = 0; j < 3; ++j) {
                    const int ij = i * 3 + j;
                    float du[3], sdu = 0.0f;
#pragma unroll
                    for (int s = 0; s < 3; ++s) {
                        float d = b[s] * wreg[s * 9 + ij];
                        if (s == j) d += ov[i] * us[s];
                        du[s] = d;
                        sdu += d;
                    }
#pragma unroll
                    for (int s = 0; s < 3; ++s)
                        row[(1 + ij) * 3 + s] = (du[s] - sdu * Z[s]) * inv_bu;
                }
            }
        }
    }

    // conv weights/bias (wave-uniform loads -> SGPRs). cw[s*27 + c*9 + ky*3 + kx]
    float cw[81];
#pragma unroll
    for (int i = 0; i < 81; ++i) cw[i] = conv_w[i];
    const float cb0 = conv_b[0], cb1 = conv_b[1], cb2 = conv_b[2];

    __syncthreads();

    float* outw = out + IMH * IMW * 3;

    // ---------- Stage B0: one thread per pixel: g0 conv + softmax -> u, p_aux;
    // then group 9 (ij=8) conv + JVP + store (fills B0's idle tail).
    if (tid < NPIX) {
        const int tx = tid & 15, ty = tid >> 4;
        const int hp = (ty + 1) * HW_ + (tx + 1);
        const int pix = (h0 + ty) * IMW + (w0 + tx);
        float y0 = cb0, y1 = cb1, y2 = cb2;
#pragma unroll
        for (int ky = 0; ky < 3; ++ky) {
#pragma unroll
            for (int kx = 0; kx < 3; ++kx) {
                const float* nb = &lds[(hp + (ky - 1) * HW_ + (kx - 1)) * ROW];
                const float v0 = nb[0], v1 = nb[1], v2 = nb[2];
                const int T = ky * 3 + kx;
                y0 += cw[0 + T] * v0 + cw[9 + T] * v1 + cw[18 + T] * v2;
                y1 += cw[27 + T] * v0 + cw[36 + T] * v1 + cw[45 + T] * v2;
                y2 += cw[54 + T] * v0 + cw[63 + T] * v1 + cw[72 + T] * v2;
            }
        }
        const float m = fmaxf(y0, fmaxf(y1, y2));
        const float e0 = __expf(y0 - m), e1 = __expf(y1 - m), e2 = __expf(y2 - m);
        const float inv = 1.0f / (e0 + e1 + e2);
        const float p0 = e0 * inv, p1 = e1 * inv, p2 = e2 * inv;
        out[pix * 3 + 0] = p0; out[pix * 3 + 1] = p1; out[pix * 3 + 2] = p2;
        p_aux4[tid] = (f4){p0, p1, p2, 0.0f};

        // group 9 (lds channels 27..29), same FMA order as the row-walk
        float a0 = 0.0f, a1 = 0.0f, a2 = 0.0f;
#pragma unroll
        for (int ky = 0; ky < 3; ++ky) {
#pragma unroll
            for (int kx = 0; kx < 3; ++kx) {
                const float* nb = &lds[(hp + (ky - 1) * HW_ + (kx - 1)) * ROW];
                const float v0 = nb[27], v1 = nb[28], v2 = nb[29];
                const int T = ky * 3 + kx;
                a0 += cw[0 + T] * v0 + cw[9 + T] * v1 + cw[18 + T] * v2;
                a1 += cw[27 + T] * v0 + cw[36 + T] * v1 + cw[45 + T] * v2;
                a2 += cw[54 + T] * v0 + cw[63 + T] * v1 + cw[72 + T] * v2;
            }
        }
        const float dot_ = p0 * a0 + p1 * a1 + p2 * a2;
        float* wp = outw + (size_t)pix * 27;
        wp[8]  = p0 * (a0 - dot_);
        wp[17] = p1 * (a1 - dot_);
        wp[26] = p2 * (a2 - dot_);
    }

    __syncthreads();

    // ---------- Stage B1: 256 threads = 16 cols x 8 groups x 2 row-halves.
    // Each walks 6 halo rows (base = half*4), producing 4 output rows via 3
    // rotating pending accumulator triplets (ky=0 newest, ky=1, ky=2 completes).
    {
        const int x = tid & 15;                 // tile column
        const int g = ((tid >> 4) & 7) + 1;     // JVP group 1..8
        const int ij = g - 1;
        const int gch = 3 * g;                  // LDS channel offset
        const int half = tid >> 7;
        const int rowb = half * 4;              // halo-row base: 0 or 4

        float a00, a01, a02;   // pending triplet A
        float b10, b11, b12;   // pending triplet B
        float c20, c21, c22;   // pending triplet C

#define ROWFMA(P0_, P1_, P2_, KY)                                                        \
        P0_ += cw[0 + (KY)*3 + 0] * v00 + cw[9 + (KY)*3 + 0] * v01 + cw[18 + (KY)*3 + 0] * v02; \
        P1_ += cw[27 + (KY)*3 + 0] * v00 + cw[36 + (KY)*3 + 0] * v01 + cw[45 + (KY)*3 + 0] * v02; \
        P2_ += cw[54 + (KY)*3 + 0] * v00 + cw[63 + (KY)*3 + 0] * v01 + cw[72 + (KY)*3 + 0] * v02; \
        P0_ += cw[0 + (KY)*3 + 1] * v10 + cw[9 + (KY)*3 + 1] * v11 + cw[18 + (KY)*3 + 1] * v12; \
        P1_ += cw[27 + (KY)*3 + 1] * v10 + cw[36 + (KY)*3 + 1] * v11 + cw[45 + (KY)*3 + 1] * v12; \
        P2_ += cw[54 + (KY)*3 + 1] * v10 + cw[63 + (KY)*3 + 1] * v11 + cw[72 + (KY)*3 + 1] * v12; \
        P0_ += cw[0 + (KY)*3 + 2] * v20 + cw[9 + (KY)*3 + 2] * v21 + cw[18 + (KY)*3 + 2] * v22; \
        P1_ += cw[27 + (KY)*3 + 2] * v20 + cw[36 + (KY)*3 + 2] * v21 + cw[45 + (KY)*3 + 2] * v22; \
        P2_ += cw[54 + (KY)*3 + 2] * v20 + cw[63 + (KY)*3 + 2] * v21 + cw[72 + (KY)*3 + 2] * v22;

#define FINISH(O, Q0, Q1, Q2) {                                                          \
        const f4 pv = p_aux4[(O) * 16 + x];                                              \
        const float dot_ = pv.x * (Q0) + pv.y * (Q1) + pv.z * (Q2);                      \
        float* wp = outw + ((size_t)((h0 + (O)) * IMW + (w0 + x))) * 27 + ij;            \
        wp[0]  = pv.x * ((Q0) - dot_);                                                   \
        wp[9]  = pv.y * ((Q1) - dot_);                                                   \
        wp[18] = pv.z * ((Q2) - dot_); }

        // DO_N/DO_M/DO_O compile-time -> dead branches fold away. R is relative
        // to rowb (runtime base; only LDS/aux addressing, rotation stays static).
#define STEP(R, N0,N1,N2, M0,M1,M2, O0,O1,O2, DO_N, DO_M, DO_O) {                        \
        const int rb = ((rowb + (R)) * HW_ + x) * ROW + gch;                             \
        const float v00 = lds[rb + 0],  v01 = lds[rb + 1],  v02 = lds[rb + 2];           \
        const float v10 = lds[rb + 31], v11 = lds[rb + 32], v12 = lds[rb + 33];          \
        const float v20 = lds[rb + 62], v21 = lds[rb + 63], v22 = lds[rb + 64];          \
        if (DO_N) { N0 = 0.0f; N1 = 0.0f; N2 = 0.0f; ROWFMA(N0, N1, N2, 0) }             \
        if (DO_M) { ROWFMA(M0, M1, M2, 1) }                                              \
        if (DO_O) { ROWFMA(O0, O1, O2, 2) FINISH(rowb + (R) - 2, O0, O1, O2) } }

        STEP(0, a00,a01,a02, b10,b11,b12, c20,c21,c22, true,  false, false)  // A:=r0
        STEP(1, b10,b11,b12, a00,a01,a02, c20,c21,c22, true,  true,  false)  // B:=r1; A ky1
        STEP(2, c20,c21,c22, b10,b11,b12, a00,a01,a02, true,  true,  true )  // C:=r2; B ky1; A fin(out0)
        STEP(3, a00,a01,a02, c20,c21,c22, b10,b11,b12, true,  true,  true )  // A:=r3; C ky1; B fin(out1)
        STEP(4, b10,b11,b12, a00,a01,a02, c20,c21,c22, false, true,  true )  // A ky1; C fin(out2)
        STEP(5, c20,c21,c22, b10,b11,b12, a00,a01,a02, false, false, true )  // A fin(out3)

#undef STEP
#undef FINISH
#undef ROWFMA
    }
}

extern "C" void kernel_launch(void* const* d_in, const int* in_sizes, int n_in,
                              void* d_out, int out_size, void* d_ws, size_t ws_size,
                              hipStream_t stream) {
    const float* obs    = (const float*)d_in[0];
    const float* P      = (const float*)d_in[1];
    const float* u_k    = (const float*)d_in[2];
    const float* w_k    = (const float*)d_in[3];
    const float* conv_w = (const float*)d_in[4];
    const float* conv_b = (const float*)d_in[5];
    float* out = (float*)d_out;

    dim3 grid(IMW / TW, IMH / TH);   // (32, 64) = 2048 blocks
    hmm_fused<<<grid, 256, 0, stream>>>(obs, P, u_k, w_k, conv_w, conv_b, out);
}